// Round 2
// 454.179 us; speedup vs baseline: 1.0037x; 1.0037x over previous
//
#include <hip/hip_runtime.h>
#include <hip/hip_bf16.h>
#include <stdint.h>

#define NROW 8192
#define INF  512
#define OUTF 256

typedef __attribute__((ext_vector_type(8))) short bf16x8;
typedef __attribute__((ext_vector_type(4))) float f32x4;

__device__ __forceinline__ unsigned short f2bf(float x) {
  union { float f; unsigned u; } v; v.f = x;
  unsigned r = v.u + 0x7fffu + ((v.u >> 16) & 1u);   // RNE
  return (unsigned short)(r >> 16);
}
__device__ __forceinline__ unsigned short f2bf_fast(float x) {
  union { float f; unsigned u; } v; v.f = x;
  return (unsigned short)((v.u + 0x8000u) >> 16);    // round-half-up
}
__device__ __forceinline__ float bf2f(unsigned short h) {
  union { unsigned u; float f; } v; v.u = ((unsigned)h) << 16;
  return v.f;
}

__device__ __forceinline__ void async_cp16(const void* g, void* l) {
  __builtin_amdgcn_global_load_lds((const __attribute__((address_space(1))) void*)g,
                                   (__attribute__((address_space(3))) void*)l,
                                   16, 0, 0);
}

// ---- k1: rowsum + A fp32 -> bf16 conversion fused (single mandatory pass over A) ----
// Reads A (268 MB), writes Abf row-major bf16 (134 MB), produces dv = rsqrt(1+rowsum).
__global__ __launch_bounds__(256) void k_rowsum_cvt(
    const float* __restrict__ A, float* __restrict__ dv,
    unsigned short* __restrict__ Abf) {
  int w = threadIdx.x >> 6, lane = threadIdx.x & 63;
  int row = blockIdx.x * 4 + w;
  const float4* ar = (const float4*)(A + (size_t)row * NROW);
  ushort4* br = (ushort4*)(Abf + (size_t)row * NROW);
  float s = 0.f;
  #pragma unroll 4
  for (int it = 0; it < NROW / 256; ++it) {
    float4 v = ar[it * 64 + lane];
    s += (v.x + v.y) + (v.z + v.w);
    ushort4 b;
    b.x = f2bf(v.x); b.y = f2bf(v.y); b.z = f2bf(v.z); b.w = f2bf(v.w);
    br[it * 64 + lane] = b;                // 512 B contiguous per wave
  }
  #pragma unroll
  for (int off = 32; off > 0; off >>= 1) s += __shfl_down(s, off, 64);
  if (lane == 0) dv[row] = rsqrtf(1.f + s);
}

// ---- k1b: plain rowsum (mid-fallback path) ----
__global__ __launch_bounds__(256) void k_rowsum(
    const float* __restrict__ A, float* __restrict__ dv) {
  int w = threadIdx.x >> 6, lane = threadIdx.x & 63;
  int row = blockIdx.x * 4 + w;
  const float4* ar = (const float4*)(A + (size_t)row * NROW);
  float s = 0.f;
  #pragma unroll 4
  for (int it = 0; it < NROW / 256; ++it) {
    float4 v = ar[it * 64 + lane];
    s += (v.x + v.y) + (v.z + v.w);
  }
  #pragma unroll
  for (int off = 32; off > 0; off >>= 1) s += __shfl_down(s, off, 64);
  if (lane == 0) dv[row] = rsqrtf(1.f + s);
}

// ---- k2: W [512][256] fp32 -> WsT [256][512] bf16 (tiny) ----
__global__ __launch_bounds__(256) void k_convert_w(
    const float* __restrict__ W, unsigned short* __restrict__ WsT) {
  int idx = blockIdx.x * 256 + threadIdx.x;  // 512*256 threads
  int k = idx >> 8, f = idx & 255;
  WsT[(size_t)f * INF + k] = f2bf(W[idx]);
}

// ---- k3: support GEMM, X read as fp32 + converted in-kernel ----
// C[f][m] = sum_k WsT[f][k]*X[m][k]; YT[f][m] = dv[m]*C. Tile 128(f) x 128(m).
__global__ __launch_bounds__(256, 2) void k_support_fx(
    const unsigned short* __restrict__ WsT,
    const float* __restrict__ X,
    const float* __restrict__ dv,
    unsigned short* __restrict__ YT) {
  __shared__ unsigned short lA[128 * 64];   // W-tile, cp16-staged (swizzled)
  __shared__ unsigned short lB[128 * 64];   // X-tile, ds_write-staged (same swizzle)
  const int t = threadIdx.x;
  const int w = t >> 6, lane = t & 63;
  const int m0 = blockIdx.x * 128;   // feature tile
  const int n0 = blockIdx.y * 128;   // node tile
  const int rsub = lane >> 3, csub = lane & 7, swz = csub ^ rsub;
  const int lr = lane & 15, lq = lane >> 4, x7 = lane & 7;
  const int mw = (w >> 1) * 64, nw = (w & 1) * 64;

  const int xrow = t >> 1, xhalf = t & 1;
  const float4* xsrc = (const float4*)(X + (size_t)(n0 + xrow) * INF + xhalf * 32);

  f32x4 acc[4][4];
  #pragma unroll
  for (int i = 0; i < 4; ++i)
    #pragma unroll
    for (int j = 0; j < 4; ++j) acc[i][j] = f32x4{0.f, 0.f, 0.f, 0.f};

  const unsigned short* ga0 = WsT + (size_t)(m0 + w * 8 + rsub) * INF + swz * 8;

  for (int it = 0; it < INF / 64; ++it) {
    __syncthreads();
    #pragma unroll
    for (int i = 0; i < 4; ++i)
      async_cp16(ga0 + (size_t)(i * 32) * INF + it * 64, &lA[(i * 32 + w * 8) * 64]);
    #pragma unroll
    for (int u = 0; u < 8; ++u) {
      float4 v = xsrc[it * 16 + u];           // k = it*64 + xhalf*32 + u*4
      ushort4 b;
      b.x = f2bf(v.x); b.y = f2bf(v.y); b.z = f2bf(v.z); b.w = f2bf(v.w);
      int k = xhalf * 32 + u * 4;
      int chunk = k >> 3, klo = k & 7;
      int slot = chunk ^ (xrow & 7);          // LDS[r][s] = G[r][s^(r&7)]
      *(ushort4*)&lB[xrow * 64 + (slot << 3) + klo] = b;
    }
    __syncthreads();
    #pragma unroll
    for (int ks = 0; ks < 2; ++ks) {
      bf16x8 af[4], bfv[4];
      #pragma unroll
      for (int mi = 0; mi < 4; ++mi)
        af[mi] = *(const bf16x8*)&lA[(mw + mi * 16 + lr) * 64 + (((ks * 4 + lq) ^ x7) << 3)];
      #pragma unroll
      for (int ni = 0; ni < 4; ++ni)
        bfv[ni] = *(const bf16x8*)&lB[(nw + ni * 16 + lr) * 64 + (((ks * 4 + lq) ^ x7) << 3)];
      #pragma unroll
      for (int mi = 0; mi < 4; ++mi)
        #pragma unroll
        for (int ni = 0; ni < 4; ++ni)
          acc[mi][ni] = __builtin_amdgcn_mfma_f32_16x16x32_bf16(
              af[mi], bfv[ni], acc[mi][ni], 0, 0, 0);
    }
  }
  #pragma unroll
  for (int mi = 0; mi < 4; ++mi) {
    #pragma unroll
    for (int ni = 0; ni < 4; ++ni) {
      f32x4 a = acc[mi][ni];
      int gr0 = m0 + mw + mi * 16 + lq * 4;    // feature
      int gc  = n0 + nw + ni * 16 + lr;        // node
      float dd = dv[gc];
      #pragma unroll
      for (int r = 0; r < 4; ++r)
        YT[(size_t)(gr0 + r) * NROW + gc] = f2bf(dd * a[r]);
    }
  }
}

// ---- k4: main GEMM reading pre-converted bf16 A via global_load_lds (zero staging VALU) ----
// P[z][m][f] = bf16( sum_{k in z-slice} Abf[m][k]*YT[f][k] ), tile 128x256, split-K=8
__global__ __launch_bounds__(256, 2) void k_gemm_main_bf16a(
    const unsigned short* __restrict__ Abf,  // [8192][8192] bf16 row-major
    const unsigned short* __restrict__ YT,   // [256][8192] bf16
    unsigned short* __restrict__ P) {        // [8][8192][256] bf16
  __shared__ unsigned short lA[128 * 64];    // 16 KB
  __shared__ unsigned short lB[256 * 64];    // 32 KB
  const int t = threadIdx.x;
  const int w = t >> 6, lane = t & 63;
  const int m0 = blockIdx.x * 128;
  const int kz = blockIdx.y * 1024;
  const int rsub = lane >> 3, csub = lane & 7, swz = csub ^ rsub;
  const int lr = lane & 15, lq = lane >> 4, x7 = lane & 7;
  const int mw = (w & 1) * 64;               // wave m-offset
  const int nw = (w >> 1) * 128;             // wave n-offset

  f32x4 acc[4][8];
  #pragma unroll
  for (int i = 0; i < 4; ++i)
    #pragma unroll
    for (int j = 0; j < 8; ++j) acc[i][j] = f32x4{0.f, 0.f, 0.f, 0.f};

  // Pre-swizzled per-lane global sources; LDS dests are wave-uniform + lane*16
  // (LDS[r][slot] = G[r][slot ^ (r&7)], r&7 == rsub for all staged sub-rows).
  const unsigned short* ga0 = Abf + (size_t)(m0 + w * 8 + rsub) * NROW + kz + swz * 8;
  const unsigned short* gb0 = YT + (size_t)(w * 8 + rsub) * NROW + kz + swz * 8;

  for (int it = 0; it < 16; ++it) {
    __syncthreads();
    #pragma unroll
    for (int i = 0; i < 8; ++i)
      async_cp16(gb0 + (size_t)(i * 32) * NROW + it * 64, &lB[(i * 32 + w * 8) * 64]);
    #pragma unroll
    for (int i = 0; i < 4; ++i)
      async_cp16(ga0 + (size_t)(i * 32) * NROW + it * 64, &lA[(i * 32 + w * 8) * 64]);
    __syncthreads();
    #pragma unroll
    for (int ks = 0; ks < 2; ++ks) {
      bf16x8 af[4], bfv[8];
      #pragma unroll
      for (int mi = 0; mi < 4; ++mi)
        af[mi] = *(const bf16x8*)&lA[(mw + mi * 16 + lr) * 64 + (((ks * 4 + lq) ^ x7) << 3)];
      #pragma unroll
      for (int ni = 0; ni < 8; ++ni)
        bfv[ni] = *(const bf16x8*)&lB[(nw + ni * 16 + lr) * 64 + (((ks * 4 + lq) ^ x7) << 3)];
      #pragma unroll
      for (int mi = 0; mi < 4; ++mi)
        #pragma unroll
        for (int ni = 0; ni < 8; ++ni)
          acc[mi][ni] = __builtin_amdgcn_mfma_f32_16x16x32_bf16(
              af[mi], bfv[ni], acc[mi][ni], 0, 0, 0);
    }
  }

  unsigned short* Pz = P + (size_t)blockIdx.y * NROW * OUTF;
  #pragma unroll
  for (int mi = 0; mi < 4; ++mi) {
    #pragma unroll
    for (int ni = 0; ni < 8; ++ni) {
      f32x4 a = acc[mi][ni];
      int gr0 = m0 + mw + mi * 16 + lq * 4;
      int gc  = nw + ni * 16 + lr;
      #pragma unroll
      for (int r = 0; r < 4; ++r)
        Pz[(size_t)(gr0 + r) * OUTF + gc] = f2bf_fast(a[r]);
    }
  }
}

// ---- k4-old: main GEMM reading A fp32 directly (mid-fallback when ws lacks Abf room) ----
__global__ __launch_bounds__(256, 2) void k_gemm_main_f32a(
    const float* __restrict__ A,
    const unsigned short* __restrict__ YT,
    unsigned short* __restrict__ P) {
  __shared__ unsigned short lA[128 * 64];
  __shared__ unsigned short lB[256 * 64];
  const int t = threadIdx.x;
  const int w = t >> 6, lane = t & 63;
  const int m0 = blockIdx.x * 128;
  const int kz = blockIdx.y * 1024;
  const int rsub = lane >> 3, csub = lane & 7, swz = csub ^ rsub;
  const int lr = lane & 15, lq = lane >> 4, x7 = lane & 7;
  const int mw = (w & 1) * 64;
  const int nw = (w >> 1) * 128;

  const int arow = t >> 2, aq = t & 3;
  const int aklo = (aq & 1) * 4;

  f32x4 acc[4][8];
  #pragma unroll
  for (int i = 0; i < 4; ++i)
    #pragma unroll
    for (int j = 0; j < 8; ++j) acc[i][j] = f32x4{0.f, 0.f, 0.f, 0.f};

  const unsigned short* gb0 = YT + (size_t)(w * 8 + rsub) * NROW + kz + swz * 8;

  for (int it = 0; it < 16; ++it) {
    __syncthreads();
    #pragma unroll
    for (int i = 0; i < 8; ++i)
      async_cp16(gb0 + (size_t)(i * 32) * NROW + it * 64, &lB[(i * 32 + w * 8) * 64]);
    #pragma unroll
    for (int h = 0; h < 2; ++h) {
      int r = arow + h * 64;
      const float4* asrc = (const float4*)(A + (size_t)(m0 + r) * NROW + kz + it * 64);
      #pragma unroll
      for (int j = 0; j < 4; ++j) {
        float4 v = asrc[aq + 4 * j];
        ushort4 b;
        b.x = f2bf_fast(v.x); b.y = f2bf_fast(v.y);
        b.z = f2bf_fast(v.z); b.w = f2bf_fast(v.w);
        int chunk = (aq + 4 * j) >> 1;
        int slot = chunk ^ (r & 7);
        *(ushort4*)&lA[r * 64 + (slot << 3) + aklo] = b;
      }
    }
    __syncthreads();
    #pragma unroll
    for (int ks = 0; ks < 2; ++ks) {
      bf16x8 af[4], bfv[8];
      #pragma unroll
      for (int mi = 0; mi < 4; ++mi)
        af[mi] = *(const bf16x8*)&lA[(mw + mi * 16 + lr) * 64 + (((ks * 4 + lq) ^ x7) << 3)];
      #pragma unroll
      for (int ni = 0; ni < 8; ++ni)
        bfv[ni] = *(const bf16x8*)&lB[(nw + ni * 16 + lr) * 64 + (((ks * 4 + lq) ^ x7) << 3)];
      #pragma unroll
      for (int mi = 0; mi < 4; ++mi)
        #pragma unroll
        for (int ni = 0; ni < 8; ++ni)
          acc[mi][ni] = __builtin_amdgcn_mfma_f32_16x16x32_bf16(
              af[mi], bfv[ni], acc[mi][ni], 0, 0, 0);
    }
  }

  unsigned short* Pz = P + (size_t)blockIdx.y * NROW * OUTF;
  #pragma unroll
  for (int mi = 0; mi < 4; ++mi) {
    #pragma unroll
    for (int ni = 0; ni < 8; ++ni) {
      f32x4 a = acc[mi][ni];
      int gr0 = m0 + mw + mi * 16 + lq * 4;
      int gc  = nw + ni * 16 + lr;
      #pragma unroll
      for (int r = 0; r < 4; ++r)
        Pz[(size_t)(gr0 + r) * OUTF + gc] = f2bf_fast(a[r]);
    }
  }
}

// ---- k5: out[i][f] = d[i] * sum_z bf2f(P[z][i][f]) ----
__global__ __launch_bounds__(256) void k_reduce8(
    const ushort4* __restrict__ P4, const float* __restrict__ dv,
    float4* __restrict__ o4) {
  int q = blockIdx.x * 256 + threadIdx.x;   // NROW*OUTF/4 threads
  const int QT = NROW * OUTF / 4;
  float4 s = {0.f, 0.f, 0.f, 0.f};
  #pragma unroll
  for (int z = 0; z < 8; ++z) {
    ushort4 v = P4[(size_t)z * QT + q];
    s.x += bf2f(v.x); s.y += bf2f(v.y); s.z += bf2f(v.z); s.w += bf2f(v.w);
  }
  float dd = dv[q >> 6];
  s.x *= dd; s.y *= dd; s.z *= dd; s.w *= dd;
  o4[q] = s;
}

// ---- fallback (ws too small): fp32, slow but correct ----
__global__ __launch_bounds__(256) void k_support_naive(
    const float* __restrict__ X, const float* __restrict__ W,
    const float* __restrict__ dv, float* __restrict__ Y) {
  __shared__ float lX[INF];
  int i = blockIdx.x;
  for (int k = threadIdx.x; k < INF; k += 256) lX[k] = X[(size_t)i * INF + k];
  __syncthreads();
  int f = threadIdx.x;
  float s = 0.f;
  for (int k = 0; k < INF; ++k) s += lX[k] * W[(size_t)k * OUTF + f];
  Y[(size_t)i * OUTF + f] = dv[i] * s;
}

__global__ __launch_bounds__(256) void k_main_naive(
    const float* __restrict__ A, const float* __restrict__ Y,
    const float* __restrict__ dv, float* __restrict__ out) {
  __shared__ float lA[256];
  int i = blockIdx.x, f = threadIdx.x;
  float s = 0.f;
  for (int jb = 0; jb < NROW; jb += 256) {
    __syncthreads();
    lA[threadIdx.x] = A[(size_t)i * NROW + jb + threadIdx.x];
    __syncthreads();
    for (int jj = 0; jj < 256; ++jj) s += lA[jj] * Y[(size_t)(jb + jj) * OUTF + f];
  }
  out[(size_t)i * OUTF + f] = dv[i] * s;
}

extern "C" void kernel_launch(void* const* d_in, const int* in_sizes, int n_in,
                              void* d_out, int out_size, void* d_ws, size_t ws_size,
                              hipStream_t stream) {
  const float* A = (const float*)d_in[0];
  const float* X = (const float*)d_in[1];
  const float* W = (const float*)d_in[2];
  float* out = (float*)d_out;

  const size_t SZ_YT  = (size_t)OUTF * NROW * 2;       // 4 MiB
  const size_t SZ_WST = (size_t)OUTF * INF * 2;        // 256 KiB
  const size_t SZ_D   = (size_t)NROW * 4;              // 32 KiB
  const size_t SZ_P   = (size_t)8 * NROW * OUTF * 2;   // 32 MiB (bf16)
  const size_t SZ_ABF = (size_t)NROW * NROW * 2;       // 128 MiB (bf16 A)
  const size_t NEED_BASE = SZ_YT + SZ_WST + SZ_D + SZ_P;
  const size_t NEED_FULL = NEED_BASE + SZ_ABF;

  char* p = (char*)d_ws;
  if (ws_size >= NEED_FULL) {
    unsigned short* YT  = (unsigned short*)p; p += SZ_YT;
    unsigned short* WsT = (unsigned short*)p; p += SZ_WST;
    float* dv = (float*)p; p += SZ_D;
    unsigned short* P = (unsigned short*)p; p += SZ_P;
    unsigned short* Abf = (unsigned short*)p;

    k_convert_w<<<dim3(512), dim3(256), 0, stream>>>(W, WsT);
    k_rowsum_cvt<<<dim3(2048), dim3(256), 0, stream>>>(A, dv, Abf);
    k_support_fx<<<dim3(2, 64), dim3(256), 0, stream>>>(WsT, X, dv, YT);
    k_gemm_main_bf16a<<<dim3(64, 8), dim3(256), 0, stream>>>(Abf, YT, P);
    k_reduce8<<<dim3(2048), dim3(256), 0, stream>>>((const ushort4*)P, dv, (float4*)out);
  } else if (ws_size >= NEED_BASE) {
    unsigned short* YT  = (unsigned short*)p; p += SZ_YT;
    unsigned short* WsT = (unsigned short*)p; p += SZ_WST;
    float* dv = (float*)p; p += SZ_D;
    unsigned short* P = (unsigned short*)p;

    k_convert_w<<<dim3(512), dim3(256), 0, stream>>>(W, WsT);
    k_rowsum<<<dim3(2048), dim3(256), 0, stream>>>(A, dv);
    k_support_fx<<<dim3(2, 64), dim3(256), 0, stream>>>(WsT, X, dv, YT);
    k_gemm_main_f32a<<<dim3(64, 8), dim3(256), 0, stream>>>(A, YT, P);
    k_reduce8<<<dim3(2048), dim3(256), 0, stream>>>((const ushort4*)P, dv, (float4*)out);
  } else {
    float* dv = (float*)p; p += SZ_D;
    float* Y  = (float*)p;
    k_rowsum<<<dim3(2048), dim3(256), 0, stream>>>(A, dv);
    k_support_naive<<<dim3(8192), dim3(256), 0, stream>>>(X, W, dv, Y);
    k_main_naive<<<dim3(8192), dim3(256), 0, stream>>>(A, Y, dv, out);
  }
}

// Round 3
// 431.977 us; speedup vs baseline: 1.0553x; 1.0514x over previous
//
#include <hip/hip_runtime.h>
#include <hip/hip_bf16.h>
#include <stdint.h>

#define NROW 8192
#define INF  512
#define OUTF 256

typedef __attribute__((ext_vector_type(8))) short bf16x8;
typedef __attribute__((ext_vector_type(4))) float f32x4;

__device__ __forceinline__ unsigned short f2bf(float x) {
  union { float f; unsigned u; } v; v.f = x;
  unsigned r = v.u + 0x7fffu + ((v.u >> 16) & 1u);   // RNE
  return (unsigned short)(r >> 16);
}
__device__ __forceinline__ unsigned short f2bf_fast(float x) {
  union { float f; unsigned u; } v; v.f = x;
  return (unsigned short)((v.u + 0x8000u) >> 16);    // round-half-up
}
__device__ __forceinline__ float bf2f(unsigned short h) {
  union { unsigned u; float f; } v; v.u = ((unsigned)h) << 16;
  return v.f;
}

__device__ __forceinline__ void async_cp16(const void* g, void* l) {
  __builtin_amdgcn_global_load_lds((const __attribute__((address_space(1))) void*)g,
                                   (__attribute__((address_space(3))) void*)l,
                                   16, 0, 0);
}

// ---- k1: rowsum + A fp32 -> bf16 conversion fused (single mandatory pass over A) ----
// A reads are NON-TEMPORAL: don't pollute L3, so the freshly written Abf (134 MB)
// stays L3-resident for k4's re-read, and its dirty lines get overwritten in-cache
// by the next poison fill instead of being written back to HBM.
__global__ __launch_bounds__(256) void k_rowsum_cvt(
    const float* __restrict__ A, float* __restrict__ dv,
    unsigned short* __restrict__ Abf) {
  int w = threadIdx.x >> 6, lane = threadIdx.x & 63;
  int row = blockIdx.x * 4 + w;
  const f32x4* ar = (const f32x4*)(A + (size_t)row * NROW);
  ushort4* br = (ushort4*)(Abf + (size_t)row * NROW);
  float s = 0.f;
  #pragma unroll 4
  for (int it = 0; it < NROW / 256; ++it) {
    f32x4 v = __builtin_nontemporal_load(&ar[it * 64 + lane]);
    s += (v.x + v.y) + (v.z + v.w);
    ushort4 b;
    b.x = f2bf(v.x); b.y = f2bf(v.y); b.z = f2bf(v.z); b.w = f2bf(v.w);
    br[it * 64 + lane] = b;                // normal store: keep Abf in L3
  }
  #pragma unroll
  for (int off = 32; off > 0; off >>= 1) s += __shfl_down(s, off, 64);
  if (lane == 0) dv[row] = rsqrtf(1.f + s);
}

// ---- k1b: plain rowsum (mid-fallback path) ----
__global__ __launch_bounds__(256) void k_rowsum(
    const float* __restrict__ A, float* __restrict__ dv) {
  int w = threadIdx.x >> 6, lane = threadIdx.x & 63;
  int row = blockIdx.x * 4 + w;
  const f32x4* ar = (const f32x4*)(A + (size_t)row * NROW);
  float s = 0.f;
  #pragma unroll 4
  for (int it = 0; it < NROW / 256; ++it) {
    f32x4 v = __builtin_nontemporal_load(&ar[it * 64 + lane]);
    s += (v.x + v.y) + (v.z + v.w);
  }
  #pragma unroll
  for (int off = 32; off > 0; off >>= 1) s += __shfl_down(s, off, 64);
  if (lane == 0) dv[row] = rsqrtf(1.f + s);
}

// ---- k2: W [512][256] fp32 -> WsT [256][512] bf16 (tiny) ----
__global__ __launch_bounds__(256) void k_convert_w(
    const float* __restrict__ W, unsigned short* __restrict__ WsT) {
  int idx = blockIdx.x * 256 + threadIdx.x;  // 512*256 threads
  int k = idx >> 8, f = idx & 255;
  WsT[(size_t)f * INF + k] = f2bf(W[idx]);
}

// ---- k3: support GEMM, X read as fp32 + converted in-kernel ----
// C[f][m] = sum_k WsT[f][k]*X[m][k]; YT[f][m] = dv[m]*C. Tile 128(f) x 128(m).
__global__ __launch_bounds__(256, 2) void k_support_fx(
    const unsigned short* __restrict__ WsT,
    const float* __restrict__ X,
    const float* __restrict__ dv,
    unsigned short* __restrict__ YT) {
  __shared__ unsigned short lA[128 * 64];   // W-tile, cp16-staged (swizzled)
  __shared__ unsigned short lB[128 * 64];   // X-tile, ds_write-staged (same swizzle)
  const int t = threadIdx.x;
  const int w = t >> 6, lane = t & 63;
  const int m0 = blockIdx.x * 128;   // feature tile
  const int n0 = blockIdx.y * 128;   // node tile
  const int rsub = lane >> 3, csub = lane & 7, swz = csub ^ rsub;
  const int lr = lane & 15, lq = lane >> 4, x7 = lane & 7;
  const int mw = (w >> 1) * 64, nw = (w & 1) * 64;

  const int xrow = t >> 1, xhalf = t & 1;
  const float4* xsrc = (const float4*)(X + (size_t)(n0 + xrow) * INF + xhalf * 32);

  f32x4 acc[4][4];
  #pragma unroll
  for (int i = 0; i < 4; ++i)
    #pragma unroll
    for (int j = 0; j < 4; ++j) acc[i][j] = f32x4{0.f, 0.f, 0.f, 0.f};

  const unsigned short* ga0 = WsT + (size_t)(m0 + w * 8 + rsub) * INF + swz * 8;

  for (int it = 0; it < INF / 64; ++it) {
    __syncthreads();
    #pragma unroll
    for (int i = 0; i < 4; ++i)
      async_cp16(ga0 + (size_t)(i * 32) * INF + it * 64, &lA[(i * 32 + w * 8) * 64]);
    #pragma unroll
    for (int u = 0; u < 8; ++u) {
      float4 v = xsrc[it * 16 + u];           // k = it*64 + xhalf*32 + u*4
      ushort4 b;
      b.x = f2bf(v.x); b.y = f2bf(v.y); b.z = f2bf(v.z); b.w = f2bf(v.w);
      int k = xhalf * 32 + u * 4;
      int chunk = k >> 3, klo = k & 7;
      int slot = chunk ^ (xrow & 7);          // LDS[r][s] = G[r][s^(r&7)]
      *(ushort4*)&lB[xrow * 64 + (slot << 3) + klo] = b;
    }
    __syncthreads();
    #pragma unroll
    for (int ks = 0; ks < 2; ++ks) {
      bf16x8 af[4], bfv[4];
      #pragma unroll
      for (int mi = 0; mi < 4; ++mi)
        af[mi] = *(const bf16x8*)&lA[(mw + mi * 16 + lr) * 64 + (((ks * 4 + lq) ^ x7) << 3)];
      #pragma unroll
      for (int ni = 0; ni < 4; ++ni)
        bfv[ni] = *(const bf16x8*)&lB[(nw + ni * 16 + lr) * 64 + (((ks * 4 + lq) ^ x7) << 3)];
      #pragma unroll
      for (int mi = 0; mi < 4; ++mi)
        #pragma unroll
        for (int ni = 0; ni < 4; ++ni)
          acc[mi][ni] = __builtin_amdgcn_mfma_f32_16x16x32_bf16(
              af[mi], bfv[ni], acc[mi][ni], 0, 0, 0);
    }
  }
  #pragma unroll
  for (int mi = 0; mi < 4; ++mi) {
    #pragma unroll
    for (int ni = 0; ni < 4; ++ni) {
      f32x4 a = acc[mi][ni];
      int gr0 = m0 + mw + mi * 16 + lq * 4;    // feature
      int gc  = n0 + nw + ni * 16 + lr;        // node
      float dd = dv[gc];
      #pragma unroll
      for (int r = 0; r < 4; ++r)
        YT[(size_t)(gr0 + r) * NROW + gc] = f2bf(dd * a[r]);
    }
  }
}

// ---- k4: main GEMM reading pre-converted bf16 A via global_load_lds (zero staging VALU) ----
// P[z][m][f] = bf16( sum_{k in z-slice} Abf[m][k]*YT[f][k] ), tile 128x256, split-K=8
__global__ __launch_bounds__(256, 2) void k_gemm_main_bf16a(
    const unsigned short* __restrict__ Abf,  // [8192][8192] bf16 row-major (L3-resident)
    const unsigned short* __restrict__ YT,   // [256][8192] bf16
    unsigned short* __restrict__ P) {        // [8][8192][256] bf16
  __shared__ unsigned short lA[128 * 64];    // 16 KB
  __shared__ unsigned short lB[256 * 64];    // 32 KB
  const int t = threadIdx.x;
  const int w = t >> 6, lane = t & 63;
  const int m0 = blockIdx.x * 128;
  const int kz = blockIdx.y * 1024;
  const int rsub = lane >> 3, csub = lane & 7, swz = csub ^ rsub;
  const int lr = lane & 15, lq = lane >> 4, x7 = lane & 7;
  const int mw = (w & 1) * 64;               // wave m-offset
  const int nw = (w >> 1) * 128;             // wave n-offset

  f32x4 acc[4][8];
  #pragma unroll
  for (int i = 0; i < 4; ++i)
    #pragma unroll
    for (int j = 0; j < 8; ++j) acc[i][j] = f32x4{0.f, 0.f, 0.f, 0.f};

  // Pre-swizzled per-lane global sources; LDS dests are wave-uniform + lane*16
  // (LDS[r][slot] = G[r][slot ^ (r&7)], r&7 == rsub for all staged sub-rows).
  const unsigned short* ga0 = Abf + (size_t)(m0 + w * 8 + rsub) * NROW + kz + swz * 8;
  const unsigned short* gb0 = YT + (size_t)(w * 8 + rsub) * NROW + kz + swz * 8;

  for (int it = 0; it < 16; ++it) {
    __syncthreads();
    #pragma unroll
    for (int i = 0; i < 8; ++i)
      async_cp16(gb0 + (size_t)(i * 32) * NROW + it * 64, &lB[(i * 32 + w * 8) * 64]);
    #pragma unroll
    for (int i = 0; i < 4; ++i)
      async_cp16(ga0 + (size_t)(i * 32) * NROW + it * 64, &lA[(i * 32 + w * 8) * 64]);
    __syncthreads();
    #pragma unroll
    for (int ks = 0; ks < 2; ++ks) {
      bf16x8 af[4], bfv[8];
      #pragma unroll
      for (int mi = 0; mi < 4; ++mi)
        af[mi] = *(const bf16x8*)&lA[(mw + mi * 16 + lr) * 64 + (((ks * 4 + lq) ^ x7) << 3)];
      #pragma unroll
      for (int ni = 0; ni < 8; ++ni)
        bfv[ni] = *(const bf16x8*)&lB[(nw + ni * 16 + lr) * 64 + (((ks * 4 + lq) ^ x7) << 3)];
      #pragma unroll
      for (int mi = 0; mi < 4; ++mi)
        #pragma unroll
        for (int ni = 0; ni < 8; ++ni)
          acc[mi][ni] = __builtin_amdgcn_mfma_f32_16x16x32_bf16(
              af[mi], bfv[ni], acc[mi][ni], 0, 0, 0);
    }
  }

  unsigned short* Pz = P + (size_t)blockIdx.y * NROW * OUTF;
  #pragma unroll
  for (int mi = 0; mi < 4; ++mi) {
    #pragma unroll
    for (int ni = 0; ni < 8; ++ni) {
      f32x4 a = acc[mi][ni];
      int gr0 = m0 + mw + mi * 16 + lq * 4;
      int gc  = nw + ni * 16 + lr;
      #pragma unroll
      for (int r = 0; r < 4; ++r)
        Pz[(size_t)(gr0 + r) * OUTF + gc] = f2bf_fast(a[r]);
    }
  }
}

// ---- k4-old: main GEMM reading A fp32 directly (mid-fallback when ws lacks Abf room) ----
__global__ __launch_bounds__(256, 2) void k_gemm_main_f32a(
    const float* __restrict__ A,
    const unsigned short* __restrict__ YT,
    unsigned short* __restrict__ P) {
  __shared__ unsigned short lA[128 * 64];
  __shared__ unsigned short lB[256 * 64];
  const int t = threadIdx.x;
  const int w = t >> 6, lane = t & 63;
  const int m0 = blockIdx.x * 128;
  const int kz = blockIdx.y * 1024;
  const int rsub = lane >> 3, csub = lane & 7, swz = csub ^ rsub;
  const int lr = lane & 15, lq = lane >> 4, x7 = lane & 7;
  const int mw = (w & 1) * 64;
  const int nw = (w >> 1) * 128;

  const int arow = t >> 2, aq = t & 3;
  const int aklo = (aq & 1) * 4;

  f32x4 acc[4][8];
  #pragma unroll
  for (int i = 0; i < 4; ++i)
    #pragma unroll
    for (int j = 0; j < 8; ++j) acc[i][j] = f32x4{0.f, 0.f, 0.f, 0.f};

  const unsigned short* gb0 = YT + (size_t)(w * 8 + rsub) * NROW + kz + swz * 8;

  for (int it = 0; it < 16; ++it) {
    __syncthreads();
    #pragma unroll
    for (int i = 0; i < 8; ++i)
      async_cp16(gb0 + (size_t)(i * 32) * NROW + it * 64, &lB[(i * 32 + w * 8) * 64]);
    #pragma unroll
    for (int h = 0; h < 2; ++h) {
      int r = arow + h * 64;
      const float4* asrc = (const float4*)(A + (size_t)(m0 + r) * NROW + kz + it * 64);
      #pragma unroll
      for (int j = 0; j < 4; ++j) {
        float4 v = asrc[aq + 4 * j];
        ushort4 b;
        b.x = f2bf_fast(v.x); b.y = f2bf_fast(v.y);
        b.z = f2bf_fast(v.z); b.w = f2bf_fast(v.w);
        int chunk = (aq + 4 * j) >> 1;
        int slot = chunk ^ (r & 7);
        *(ushort4*)&lA[r * 64 + (slot << 3) + aklo] = b;
      }
    }
    __syncthreads();
    #pragma unroll
    for (int ks = 0; ks < 2; ++ks) {
      bf16x8 af[4], bfv[8];
      #pragma unroll
      for (int mi = 0; mi < 4; ++mi)
        af[mi] = *(const bf16x8*)&lA[(mw + mi * 16 + lr) * 64 + (((ks * 4 + lq) ^ x7) << 3)];
      #pragma unroll
      for (int ni = 0; ni < 8; ++ni)
        bfv[ni] = *(const bf16x8*)&lB[(nw + ni * 16 + lr) * 64 + (((ks * 4 + lq) ^ x7) << 3)];
      #pragma unroll
      for (int mi = 0; mi < 4; ++mi)
        #pragma unroll
        for (int ni = 0; ni < 8; ++ni)
          acc[mi][ni] = __builtin_amdgcn_mfma_f32_16x16x32_bf16(
              af[mi], bfv[ni], acc[mi][ni], 0, 0, 0);
    }
  }

  unsigned short* Pz = P + (size_t)blockIdx.y * NROW * OUTF;
  #pragma unroll
  for (int mi = 0; mi < 4; ++mi) {
    #pragma unroll
    for (int ni = 0; ni < 8; ++ni) {
      f32x4 a = acc[mi][ni];
      int gr0 = m0 + mw + mi * 16 + lq * 4;
      int gc  = nw + ni * 16 + lr;
      #pragma unroll
      for (int r = 0; r < 4; ++r)
        Pz[(size_t)(gr0 + r) * OUTF + gc] = f2bf_fast(a[r]);
    }
  }
}

// ---- k5: out[i][f] = d[i] * sum_z bf2f(P[z][i][f]) ----
__global__ __launch_bounds__(256) void k_reduce8(
    const ushort4* __restrict__ P4, const float* __restrict__ dv,
    float4* __restrict__ o4) {
  int q = blockIdx.x * 256 + threadIdx.x;   // NROW*OUTF/4 threads
  const int QT = NROW * OUTF / 4;
  float4 s = {0.f, 0.f, 0.f, 0.f};
  #pragma unroll
  for (int z = 0; z < 8; ++z) {
    ushort4 v = P4[(size_t)z * QT + q];
    s.x += bf2f(v.x); s.y += bf2f(v.y); s.z += bf2f(v.z); s.w += bf2f(v.w);
  }
  float dd = dv[q >> 6];
  s.x *= dd; s.y *= dd; s.z *= dd; s.w *= dd;
  o4[q] = s;
}

// ---- fallback (ws too small): fp32, slow but correct ----
__global__ __launch_bounds__(256) void k_support_naive(
    const float* __restrict__ X, const float* __restrict__ W,
    const float* __restrict__ dv, float* __restrict__ Y) {
  __shared__ float lX[INF];
  int i = blockIdx.x;
  for (int k = threadIdx.x; k < INF; k += 256) lX[k] = X[(size_t)i * INF + k];
  __syncthreads();
  int f = threadIdx.x;
  float s = 0.f;
  for (int k = 0; k < INF; ++k) s += lX[k] * W[(size_t)k * OUTF + f];
  Y[(size_t)i * OUTF + f] = dv[i] * s;
}

__global__ __launch_bounds__(256) void k_main_naive(
    const float* __restrict__ A, const float* __restrict__ Y,
    const float* __restrict__ dv, float* __restrict__ out) {
  __shared__ float lA[256];
  int i = blockIdx.x, f = threadIdx.x;
  float s = 0.f;
  for (int jb = 0; jb < NROW; jb += 256) {
    __syncthreads();
    lA[threadIdx.x] = A[(size_t)i * NROW + jb + threadIdx.x];
    __syncthreads();
    for (int jj = 0; jj < 256; ++jj) s += lA[jj] * Y[(size_t)(jb + jj) * OUTF + f];
  }
  out[(size_t)i * OUTF + f] = dv[i] * s;
}

extern "C" void kernel_launch(void* const* d_in, const int* in_sizes, int n_in,
                              void* d_out, int out_size, void* d_ws, size_t ws_size,
                              hipStream_t stream) {
  const float* A = (const float*)d_in[0];
  const float* X = (const float*)d_in[1];
  const float* W = (const float*)d_in[2];
  float* out = (float*)d_out;

  const size_t SZ_YT  = (size_t)OUTF * NROW * 2;       // 4 MiB
  const size_t SZ_WST = (size_t)OUTF * INF * 2;        // 256 KiB
  const size_t SZ_D   = (size_t)NROW * 4;              // 32 KiB
  const size_t SZ_P   = (size_t)8 * NROW * OUTF * 2;   // 32 MiB (bf16)
  const size_t SZ_ABF = (size_t)NROW * NROW * 2;       // 128 MiB (bf16 A)
  const size_t NEED_BASE = SZ_YT + SZ_WST + SZ_D + SZ_P;
  const size_t NEED_FULL = NEED_BASE + SZ_ABF;

  char* p = (char*)d_ws;
  if (ws_size >= NEED_FULL) {
    unsigned short* YT  = (unsigned short*)p; p += SZ_YT;
    unsigned short* WsT = (unsigned short*)p; p += SZ_WST;
    float* dv = (float*)p; p += SZ_D;
    unsigned short* P = (unsigned short*)p; p += SZ_P;
    unsigned short* Abf = (unsigned short*)p;

    k_convert_w<<<dim3(512), dim3(256), 0, stream>>>(W, WsT);
    k_rowsum_cvt<<<dim3(2048), dim3(256), 0, stream>>>(A, dv, Abf);
    k_support_fx<<<dim3(2, 64), dim3(256), 0, stream>>>(WsT, X, dv, YT);
    k_gemm_main_bf16a<<<dim3(64, 8), dim3(256), 0, stream>>>(Abf, YT, P);
    k_reduce8<<<dim3(2048), dim3(256), 0, stream>>>((const ushort4*)P, dv, (float4*)out);
  } else if (ws_size >= NEED_BASE) {
    unsigned short* YT  = (unsigned short*)p; p += SZ_YT;
    unsigned short* WsT = (unsigned short*)p; p += SZ_WST;
    float* dv = (float*)p; p += SZ_D;
    unsigned short* P = (unsigned short*)p;

    k_convert_w<<<dim3(512), dim3(256), 0, stream>>>(W, WsT);
    k_rowsum<<<dim3(2048), dim3(256), 0, stream>>>(A, dv);
    k_support_fx<<<dim3(2, 64), dim3(256), 0, stream>>>(WsT, X, dv, YT);
    k_gemm_main_f32a<<<dim3(64, 8), dim3(256), 0, stream>>>(A, YT, P);
    k_reduce8<<<dim3(2048), dim3(256), 0, stream>>>((const ushort4*)P, dv, (float4*)out);
  } else {
    float* dv = (float*)p; p += SZ_D;
    float* Y  = (float*)p;
    k_rowsum<<<dim3(2048), dim3(256), 0, stream>>>(A, dv);
    k_support_naive<<<dim3(8192), dim3(256), 0, stream>>>(X, W, dv, Y);
    k_main_naive<<<dim3(8192), dim3(256), 0, stream>>>(A, Y, dv, out);
  }
}